// Round 6
// baseline (445.635 us; speedup 1.0000x reference)
//
#include <hip/hip_runtime.h>
#include <hip/hip_bf16.h>
#include <cstddef>

#define B_   256
#define P_   196
#define DE_  2048
#define DD_  512
#define DA_  512
#define M_   (B_*P_)   // 50176

#define BM   64        // grid 784 exact
#define KT   32        // K per step
#define NKT  (DE_/KT)  // 64

typedef __attribute__((ext_vector_type(4))) float f32x4;
typedef __attribute__((ext_vector_type(8))) short s16x8;

static __device__ __forceinline__ short f2bf(float x) {
    __hip_bfloat16 h = __float2bfloat16(x);
    return *reinterpret_cast<short*>(&h);
}

// ---------------------------------------------------------------------------
// Kernel 0: pack W_enc [K][N] fp32 -> bf16 per-fragment layout:
//   unit u = (kt*32 + gf)*64 + lane  (unit = 8 bf16 = 16 B)
//   content: lane l, j -> W[kt*32 + (l>>4)*8 + j][gf*16 + (l&15)]
// ---------------------------------------------------------------------------
__global__ __launch_bounds__(256) void pack_wenc(
        const float* __restrict__ W, __hip_bfloat16* __restrict__ out) {
    __shared__ float lds[KT][DA_];          // 64 KB
    const int kt = blockIdx.x;
    const int t  = threadIdx.x;
#pragma unroll
    for (int i = 0; i < 64; ++i) {
        int e = i * 256 + t;
        int k = e >> 9, n = e & 511;
        lds[k][n] = W[(size_t)(kt * KT + k) * DA_ + n];
    }
    __syncthreads();
    short* o = reinterpret_cast<short*>(out) + (size_t)kt * (32 * 64 * 8);
#pragma unroll
    for (int i = 0; i < 8; ++i) {
        int idx  = i * 256 + t;
        int gf   = idx >> 6;
        int lane = idx & 63;
        int g = lane >> 4, c = lane & 15;
        s16x8 w;
#pragma unroll
        for (int j = 0; j < 8; ++j)
            w[j] = f2bf(lds[g * 8 + j][gf * 16 + c]);
        *reinterpret_cast<s16x8*>(o + (size_t)idx * 8) = w;
    }
}

// ---------------------------------------------------------------------------
// Kernel 1: att2p[b][a] = dh[b,:] @ W_dec[:,a] + b_dec[a] + b_enc[a]
// ---------------------------------------------------------------------------
__global__ __launch_bounds__(512) void att2_kernel(
        const float* __restrict__ dh, const float* __restrict__ W_dec,
        const float* __restrict__ b_dec, const float* __restrict__ b_enc,
        float* __restrict__ att2p) {
    __shared__ float s_dh[DD_];
    const int b = blockIdx.x;
    const int a = threadIdx.x;
    s_dh[a] = dh[(size_t)b * DD_ + a];
    __syncthreads();
    float acc = 0.f;
#pragma unroll 8
    for (int k = 0; k < DD_; ++k)
        acc += s_dh[k] * W_dec[(size_t)k * DA_ + a];
    att2p[(size_t)b * DA_ + a] = acc + b_dec[a] + b_enc[a];
}

// ---------------------------------------------------------------------------
// Kernel 2: GEMM 50176x512x2048 bf16 MFMA, ALL-REGISTER K-loop:
//   no LDS, no barriers. 4 waves/block, each owns 64 rows x 128 cols.
//   A: HBM -> VGPR (fp32, 1-step prefetch) -> cvt bf16.  B: L2 -> VGPR.
//   Fused relu/dot epilogue; single __syncthreads for cross-wave reduce.
// ---------------------------------------------------------------------------
__global__ __launch_bounds__(256, 2) void gemm_att(
        const float* __restrict__ enc, const __hip_bfloat16* __restrict__ Bp,
        const float* __restrict__ att2p, const float* __restrict__ Wfull,
        const float* __restrict__ bfull, float* __restrict__ att) {
    __shared__ float red[BM][4];            // 1 KB only

    const int tid  = threadIdx.x;
    const int wave = tid >> 6;
    const int lane = tid & 63;
    const int g    = lane >> 4;             // k-group 0..3
    const int c    = lane & 15;             // row (A) / col (B) in frag
    const int block_row = blockIdx.x * BM;
    const int nbase = wave * 128;

    // A: lane (g,c), m-frag mt reads enc[block_row + mt*16 + c][t*32 + g*8 .. +8)
    const float* aptr = enc + (size_t)(block_row + c) * DE_ + g * 8;
    // B: frag (t, nt) for this wave at unit ((t*32 + wave*8 + nt)*64 + lane)
    const s16x8* bp = reinterpret_cast<const s16x8*>(Bp) + (size_t)(wave * 8) * 64 + lane;

    f32x4 acc[4][8] = {};
    f32x4 pa[4][2];          // A(t+1) fp32 prefetch
    s16x8 af[4], bf[8];

#define LOAD_A_T(T) do {                                                 \
        _Pragma("unroll")                                                \
        for (int mt_ = 0; mt_ < 4; ++mt_) {                              \
            const float* p_ = aptr + (size_t)mt_ * (16 * DE_) + (T) * KT;\
            pa[mt_][0] = *reinterpret_cast<const f32x4*>(p_);            \
            pa[mt_][1] = *reinterpret_cast<const f32x4*>(p_ + 4);        \
        }                                                                \
    } while (0)

#define CVT_A() do {                                                     \
        _Pragma("unroll")                                                \
        for (int mt_ = 0; mt_ < 4; ++mt_) {                              \
            s16x8 w_;                                                    \
            w_[0]=f2bf(pa[mt_][0].x); w_[1]=f2bf(pa[mt_][0].y);          \
            w_[2]=f2bf(pa[mt_][0].z); w_[3]=f2bf(pa[mt_][0].w);          \
            w_[4]=f2bf(pa[mt_][1].x); w_[5]=f2bf(pa[mt_][1].y);          \
            w_[6]=f2bf(pa[mt_][1].z); w_[7]=f2bf(pa[mt_][1].w);          \
            af[mt_] = w_;                                                \
        }                                                                \
    } while (0)

#define LOAD_B_T(T) do {                                                 \
        _Pragma("unroll")                                                \
        for (int nt_ = 0; nt_ < 8; ++nt_)                                \
            bf[nt_] = bp[(size_t)(T) * 2048 + nt_ * 64];                 \
    } while (0)

#define MFMA_STEP() do {                                                 \
        _Pragma("unroll")                                                \
        for (int nt_ = 0; nt_ < 8; ++nt_)                                \
            _Pragma("unroll")                                            \
            for (int mt_ = 0; mt_ < 4; ++mt_)                            \
                acc[mt_][nt_] = __builtin_amdgcn_mfma_f32_16x16x32_bf16( \
                                    af[mt_], bf[nt_], acc[mt_][nt_], 0, 0, 0); \
    } while (0)

    // ---- prologue: af/bf = step 0, pa = A(1) in flight ----
    LOAD_A_T(0);
    LOAD_B_T(0);
    CVT_A();                 // waits A(0)
    LOAD_A_T(1);

#pragma clang loop unroll(disable)
    for (int t = 0; t < NKT; ++t) {
        MFMA_STEP();                         // consume af/bf = step t
        const int t1 = (t + 1 < NKT) ? t + 1 : NKT - 1;
        const int t2 = (t + 2 < NKT) ? t + 2 : NKT - 1;
        LOAD_B_T(t1);                        // B(t+1) -> bf (after consumption)
        CVT_A();                             // A(t+1): pa -> af (vmcnt wait)
        LOAD_A_T(t2);                        // A(t+2) -> pa
    }

    // ---- fused epilogue: att[R] = sum_n relu(att1+att2)*Wfull ----
    const int b0    = block_row / P_;
    const int b1    = min(b0 + 1, B_ - 1);
    const int split = (b0 + 1) * P_;
    float wf[8], a20[8], a21[8];
#pragma unroll
    for (int nt = 0; nt < 8; ++nt) {
        const int n = nbase + nt * 16 + c;
        wf[nt]  = Wfull[n];
        a20[nt] = att2p[(size_t)b0 * DA_ + n];
        a21[nt] = att2p[(size_t)b1 * DA_ + n];
    }
#pragma unroll
    for (int mt = 0; mt < 4; ++mt) {
#pragma unroll
        for (int q = 0; q < 4; ++q) {
            const int row_local = mt * 16 + g * 4 + q;
            const int R = block_row + row_local;
            const bool hi = (R >= split);
            float s = 0.f;
#pragma unroll
            for (int nt = 0; nt < 8; ++nt) {
                float a2 = hi ? a21[nt] : a20[nt];
                float v  = acc[mt][nt][q] + a2;
                v = fmaxf(v, 0.f);
                s += v * wf[nt];
            }
#pragma unroll
            for (int off = 1; off < 16; off <<= 1)
                s += __shfl_xor(s, off, 64);
            if (c == 0) red[row_local][wave] = s;
        }
    }
    __syncthreads();
    if (tid < BM) {
        float t = 0.f;
#pragma unroll
        for (int w = 0; w < 4; ++w) t += red[tid][w];
        att[block_row + tid] = t + bfull[0];
    }
#undef LOAD_A_T
#undef CVT_A
#undef LOAD_B_T
#undef MFMA_STEP
}

// ---------------------------------------------------------------------------
// Kernel 3: softmax over P per batch -> alpha
// ---------------------------------------------------------------------------
__global__ __launch_bounds__(256) void softmax_kernel(
        const float* __restrict__ att, float* __restrict__ alpha) {
    const int b = blockIdx.x;
    const int t = threadIdx.x;
    __shared__ float sred[4];
    float v = (t < P_) ? att[(size_t)b * P_ + t] : -1e30f;
    float m = v;
#pragma unroll
    for (int off = 1; off < 64; off <<= 1) m = fmaxf(m, __shfl_xor(m, off, 64));
    if ((t & 63) == 0) sred[t >> 6] = m;
    __syncthreads();
    const float mall = fmaxf(fmaxf(sred[0], sred[1]), fmaxf(sred[2], sred[3]));
    __syncthreads();
    float e = (t < P_) ? expf(v - mall) : 0.f;
    float s = e;
#pragma unroll
    for (int off = 1; off < 64; off <<= 1) s += __shfl_xor(s, off, 64);
    if ((t & 63) == 0) sred[t >> 6] = s;
    __syncthreads();
    const float stot = sred[0] + sred[1] + sred[2] + sred[3];
    if (t < P_) alpha[(size_t)b * P_ + t] = e / stot;
}

// ---------------------------------------------------------------------------
// Kernel 4: context[b][e] = sum_p alpha[b][p] * enc[b][p][e]
// ---------------------------------------------------------------------------
__global__ __launch_bounds__(256) void context_kernel(
        const float* __restrict__ enc, const float* __restrict__ alpha,
        float* __restrict__ ctx) {
    const int b = blockIdx.x;
    const int e = blockIdx.y * 1024 + threadIdx.x * 4;
    __shared__ float s_alpha[P_];
    if (threadIdx.x < P_) s_alpha[threadIdx.x] = alpha[(size_t)b * P_ + threadIdx.x];
    __syncthreads();
    f32x4 acc = {0.f, 0.f, 0.f, 0.f};
    const float* base = enc + (size_t)b * P_ * DE_ + e;
#pragma unroll 4
    for (int p = 0; p < P_; ++p) {
        f32x4 v = *reinterpret_cast<const f32x4*>(base + (size_t)p * DE_);
        acc += s_alpha[p] * v;
    }
    *reinterpret_cast<f32x4*>(ctx + (size_t)b * DE_ + e) = acc;
}

// ---------------------------------------------------------------------------
extern "C" void kernel_launch(void* const* d_in, const int* in_sizes, int n_in,
                              void* d_out, int out_size, void* d_ws, size_t ws_size,
                              hipStream_t stream) {
    const float* enc    = (const float*)d_in[0];
    const float* dh     = (const float*)d_in[1];
    const float* W_enc  = (const float*)d_in[2];
    const float* b_enc  = (const float*)d_in[3];
    const float* W_dec  = (const float*)d_in[4];
    const float* b_dec  = (const float*)d_in[5];
    const float* W_full = (const float*)d_in[6];
    const float* b_full = (const float*)d_in[7];

    float* out       = (float*)d_out;
    float* ctx_out   = out;                       // [B,DE]
    float* alpha_out = out + (size_t)B_ * DE_;    // [B,P]

    char* ws = (char*)d_ws;
    __hip_bfloat16* Bp = (__hip_bfloat16*)ws;                        // 2 MB
    float* att2p = (float*)(ws + 2u * 1024 * 1024);                  // 512 KB
    float* att   = (float*)(ws + 2u * 1024 * 1024 + 512u * 1024);    // 200 KB

    pack_wenc   <<<NKT,             256, 0, stream>>>(W_enc, Bp);
    att2_kernel <<<B_,              512, 0, stream>>>(dh, W_dec, b_dec, b_enc, att2p);
    gemm_att    <<<M_ / BM,         256, 0, stream>>>(enc, Bp, att2p, W_full, b_full, att);
    softmax_kernel<<<B_,            256, 0, stream>>>(att, alpha_out);
    context_kernel<<<dim3(B_, 2),   256, 0, stream>>>(enc, alpha_out, ctx_out);
}

// Round 7
// 279.760 us; speedup vs baseline: 1.5929x; 1.5929x over previous
//
#include <hip/hip_runtime.h>
#include <hip/hip_bf16.h>
#include <cstddef>

#define B_   256
#define P_   196
#define DE_  2048
#define DD_  512
#define DA_  512
#define M_   (B_*P_)   // 50176

#define BM   64
#define KT   32
#define NKT  (DE_/KT)  // 64

typedef __attribute__((ext_vector_type(4))) float f32x4;
typedef __attribute__((ext_vector_type(8))) short s16x8;

static __device__ __forceinline__ short f2bf(float x) {
    __hip_bfloat16 h = __float2bfloat16(x);
    return *reinterpret_cast<short*>(&h);
}

// ---------------------------------------------------------------------------
// Kernel 0: pack W_enc [K][N] fp32 -> bf16 per-fragment layout:
//   unit u = (kt*32 + gf)*64 + lane  (unit = 8 bf16 = 16 B)
//   content: lane l, j -> W[kt*32 + (l>>4)*8 + j][gf*16 + (l&15)]
// ---------------------------------------------------------------------------
__global__ __launch_bounds__(256) void pack_wenc(
        const float* __restrict__ W, __hip_bfloat16* __restrict__ out) {
    __shared__ float lds[KT][DA_];          // 64 KB
    const int kt = blockIdx.x;
    const int t  = threadIdx.x;
#pragma unroll
    for (int i = 0; i < 64; ++i) {
        int e = i * 256 + t;
        int k = e >> 9, n = e & 511;
        lds[k][n] = W[(size_t)(kt * KT + k) * DA_ + n];
    }
    __syncthreads();
    short* o = reinterpret_cast<short*>(out) + (size_t)kt * (32 * 64 * 8);
#pragma unroll
    for (int i = 0; i < 8; ++i) {
        int idx  = i * 256 + t;
        int gf   = idx >> 6;
        int lane = idx & 63;
        int g = lane >> 4, c = lane & 15;
        s16x8 w;
#pragma unroll
        for (int j = 0; j < 8; ++j)
            w[j] = f2bf(lds[g * 8 + j][gf * 16 + c]);
        *reinterpret_cast<s16x8*>(o + (size_t)idx * 8) = w;
    }
}

// ---------------------------------------------------------------------------
// Kernel 1: att2p[b][a] = dh[b,:] @ W_dec[:,a] + b_dec[a] + b_enc[a]
// ---------------------------------------------------------------------------
__global__ __launch_bounds__(512) void att2_kernel(
        const float* __restrict__ dh, const float* __restrict__ W_dec,
        const float* __restrict__ b_dec, const float* __restrict__ b_enc,
        float* __restrict__ att2p) {
    __shared__ float s_dh[DD_];
    const int b = blockIdx.x;
    const int a = threadIdx.x;
    s_dh[a] = dh[(size_t)b * DD_ + a];
    __syncthreads();
    float acc = 0.f;
#pragma unroll 8
    for (int k = 0; k < DD_; ++k)
        acc += s_dh[k] * W_dec[(size_t)k * DA_ + a];
    att2p[(size_t)b * DA_ + a] = acc + b_dec[a] + b_enc[a];
}

// ---------------------------------------------------------------------------
// Kernel 2: GEMM, tile 64 rows x 256 cols (N split in 2), 4 waves (wave=64x64,
// acc[4][4]=64 AGPR). B: L2->VGPR double-buffered (2-step cover). A: HBM->reg
// (2-step) -> bf16 -> 4KB LDS dbuf; raw s_barrier + lgkmcnt only.
// Pairing: physical bid p -> mt=(p>>4)*8+(p&7), nh=(p>>3)&1, so the two
// N-halves of an M-tile are 8 apart (same XCD rr-slot -> A L2/L3 reuse).
// Partial relu-dot goes to att0/att1; softmax sums them (deterministic).
// ---------------------------------------------------------------------------
__global__ __launch_bounds__(256, 3) void gemm_att(
        const float* __restrict__ enc, const __hip_bfloat16* __restrict__ Bp,
        const float* __restrict__ att2p, const float* __restrict__ Wfull,
        float* __restrict__ att0, float* __restrict__ att1) {
    __shared__ __hip_bfloat16 a_lds0[BM * KT];   // 4 KB
    __shared__ __hip_bfloat16 a_lds1[BM * KT];   // 4 KB
    __shared__ float red[BM][4];                 // 1 KB

    const int tid  = threadIdx.x;
    const int wave = tid >> 6;
    const int lane = tid & 63;
    const int g    = lane >> 4;
    const int c    = lane & 15;

    const int p   = blockIdx.x;
    const int mt_ = (p >> 4) * 8 + (p & 7);      // 0..783
    const int nh  = (p >> 3) & 1;                // N-half
    const int block_row = mt_ * BM;

    const int slot8 = (g ^ ((c >> 1) & 3)) * 8;

    // A staging: thread -> row tid>>2, k-slot tid&3 (8 floats)
    const int ar = tid >> 2;
    const int aq = tid & 3;
    const int a_woff = ar * KT + (aq ^ ((ar >> 1) & 3)) * 8;
    const float* ap = enc + (size_t)(block_row + ar) * DE_ + aq * 8;

    // B frags: gf = nh*16 + wave*4 + nt
    const s16x8* bp = reinterpret_cast<const s16x8*>(Bp)
                    + ((size_t)(nh * 16 + wave * 4)) * 64 + lane;

    f32x4 acc[4][4] = {};
    f32x4 pX0, pX1, pY0, pY1;        // A prefetch sets (8 floats each)
    s16x8 bfX[4], bfY[4];            // B double buffer

#define ISSUE_A(v0, v1, T) do {                                          \
        const int tt_ = (T) > 63 ? 63 : (T);                             \
        v0 = *reinterpret_cast<const f32x4*>(ap + tt_ * KT);             \
        v1 = *reinterpret_cast<const f32x4*>(ap + tt_ * KT + 4);         \
    } while (0)

#define ISSUE_B(dst, T) do {                                             \
        _Pragma("unroll")                                                \
        for (int nt_ = 0; nt_ < 4; ++nt_)                                \
            dst[nt_] = bp[((size_t)(T) * 32 + nt_) * 64];                \
    } while (0)

#define STORE_A(dst, v0, v1) do {                                        \
        s16x8 w_;                                                        \
        w_[0]=f2bf((v0).x); w_[1]=f2bf((v0).y); w_[2]=f2bf((v0).z); w_[3]=f2bf((v0).w); \
        w_[4]=f2bf((v1).x); w_[5]=f2bf((v1).y); w_[6]=f2bf((v1).z); w_[7]=f2bf((v1).w); \
        *reinterpret_cast<s16x8*>((dst) + a_woff) = w_;                  \
    } while (0)

#define FRAGS_MFMA(abuf, bfr) do {                                       \
        s16x8 af[4];                                                     \
        _Pragma("unroll")                                                \
        for (int mt2 = 0; mt2 < 4; ++mt2)                                \
            af[mt2] = *reinterpret_cast<const s16x8*>((abuf) + (mt2*16 + c) * KT + slot8); \
        _Pragma("unroll")                                                \
        for (int nt2 = 0; nt2 < 4; ++nt2)                                \
            _Pragma("unroll")                                            \
            for (int mt2 = 0; mt2 < 4; ++mt2)                            \
                acc[mt2][nt2] = __builtin_amdgcn_mfma_f32_16x16x32_bf16( \
                                    af[mt2], bfr[nt2], acc[mt2][nt2], 0, 0, 0); \
    } while (0)

#define BAR() do {                                                       \
        asm volatile("s_waitcnt lgkmcnt(0)" ::: "memory");               \
        __builtin_amdgcn_s_barrier();                                    \
        __builtin_amdgcn_sched_barrier(0);                               \
    } while (0)

    // ---- prologue ----
    ISSUE_A(pX0, pX1, 0);            // A(0)
    ISSUE_A(pY0, pY1, 1);            // A(1)
    ISSUE_B(bfX, 0);                 // B(0)
    STORE_A(a_lds0, pX0, pX1);       // waits A(0) (FIFO)
    ISSUE_A(pX0, pX1, 2);            // A(2)
    ISSUE_B(bfY, 1);                 // B(1)
    BAR();

#pragma clang loop unroll(disable)
    for (int t = 0; t < 62; t += 2) {
        // even step t: compute(lds0, bfX=B(t))
        STORE_A(a_lds1, pY0, pY1);   // A(t+1)
        ISSUE_A(pY0, pY1, t + 3);
        FRAGS_MFMA(a_lds0, bfX);
        ISSUE_B(bfX, t + 2);         // B(t+2), consumed 2 steps later
        BAR();
        // odd step t+1: compute(lds1, bfY=B(t+1))
        STORE_A(a_lds0, pX0, pX1);   // A(t+2)
        ISSUE_A(pX0, pX1, t + 4);
        FRAGS_MFMA(a_lds1, bfY);
        ISSUE_B(bfY, t + 3);         // B(t+3)
        BAR();
    }
    // step 62: compute(lds0=A(62), bfX=B(62)); stage A(63)
    STORE_A(a_lds1, pY0, pY1);
    FRAGS_MFMA(a_lds0, bfX);
    BAR();
    // step 63: compute(lds1=A(63), bfY=B(63))
    FRAGS_MFMA(a_lds1, bfY);

    // ---- fused epilogue: partial dot over this block's 256 cols ----
    const int b0    = block_row / P_;
    const int b1    = min(b0 + 1, B_ - 1);
    const int split = (b0 + 1) * P_;
    const int ncol0 = nh * 256 + wave * 64;
    float wf[4], a20[4], a21[4];
#pragma unroll
    for (int nt = 0; nt < 4; ++nt) {
        const int n = ncol0 + nt * 16 + c;
        wf[nt]  = Wfull[n];
        a20[nt] = att2p[(size_t)b0 * DA_ + n];
        a21[nt] = att2p[(size_t)b1 * DA_ + n];
    }
#pragma unroll
    for (int mt = 0; mt < 4; ++mt) {
#pragma unroll
        for (int q = 0; q < 4; ++q) {
            const int row_local = mt * 16 + g * 4 + q;
            const int R = block_row + row_local;
            const bool hi = (R >= split);
            float s = 0.f;
#pragma unroll
            for (int nt = 0; nt < 4; ++nt) {
                float a2 = hi ? a21[nt] : a20[nt];
                float v  = acc[mt][nt][q] + a2;
                v = fmaxf(v, 0.f);
                s += v * wf[nt];
            }
#pragma unroll
            for (int off = 1; off < 16; off <<= 1)
                s += __shfl_xor(s, off, 64);
            if (c == 0) red[row_local][wave] = s;
        }
    }
    __syncthreads();
    if (tid < BM) {
        float t = red[tid][0] + red[tid][1] + red[tid][2] + red[tid][3];
        float* dst = nh ? att1 : att0;
        dst[block_row + tid] = t;
    }
#undef ISSUE_A
#undef ISSUE_B
#undef STORE_A
#undef FRAGS_MFMA
#undef BAR
}

// ---------------------------------------------------------------------------
// Kernel 3: softmax over P per batch -> alpha  (att = att0 + att1; bfull
// dropped: softmax is shift-invariant)
// ---------------------------------------------------------------------------
__global__ __launch_bounds__(256) void softmax_kernel(
        const float* __restrict__ att0, const float* __restrict__ att1,
        float* __restrict__ alpha) {
    const int b = blockIdx.x;
    const int t = threadIdx.x;
    __shared__ float sred[4];
    float v = -1e30f;
    if (t < P_) v = att0[(size_t)b * P_ + t] + att1[(size_t)b * P_ + t];
    float m = v;
#pragma unroll
    for (int off = 1; off < 64; off <<= 1) m = fmaxf(m, __shfl_xor(m, off, 64));
    if ((t & 63) == 0) sred[t >> 6] = m;
    __syncthreads();
    const float mall = fmaxf(fmaxf(sred[0], sred[1]), fmaxf(sred[2], sred[3]));
    __syncthreads();
    float e = (t < P_) ? expf(v - mall) : 0.f;
    float s = e;
#pragma unroll
    for (int off = 1; off < 64; off <<= 1) s += __shfl_xor(s, off, 64);
    if ((t & 63) == 0) sred[t >> 6] = s;
    __syncthreads();
    const float stot = sred[0] + sred[1] + sred[2] + sred[3];
    if (t < P_) alpha[(size_t)b * P_ + t] = e / stot;
}

// ---------------------------------------------------------------------------
// Kernel 4: context[b][e] = sum_p alpha[b][p] * enc[b][p][e]
// ---------------------------------------------------------------------------
__global__ __launch_bounds__(256) void context_kernel(
        const float* __restrict__ enc, const float* __restrict__ alpha,
        float* __restrict__ ctx) {
    const int b = blockIdx.x;
    const int e = blockIdx.y * 1024 + threadIdx.x * 4;
    __shared__ float s_alpha[P_];
    if (threadIdx.x < P_) s_alpha[threadIdx.x] = alpha[(size_t)b * P_ + threadIdx.x];
    __syncthreads();
    f32x4 acc = {0.f, 0.f, 0.f, 0.f};
    const float* base = enc + (size_t)b * P_ * DE_ + e;
#pragma unroll 4
    for (int p = 0; p < P_; ++p) {
        f32x4 v = *reinterpret_cast<const f32x4*>(base + (size_t)p * DE_);
        acc += s_alpha[p] * v;
    }
    *reinterpret_cast<f32x4*>(ctx + (size_t)b * DE_ + e) = acc;
}

// ---------------------------------------------------------------------------
extern "C" void kernel_launch(void* const* d_in, const int* in_sizes, int n_in,
                              void* d_out, int out_size, void* d_ws, size_t ws_size,
                              hipStream_t stream) {
    const float* enc    = (const float*)d_in[0];
    const float* dh     = (const float*)d_in[1];
    const float* W_enc  = (const float*)d_in[2];
    const float* b_enc  = (const float*)d_in[3];
    const float* W_dec  = (const float*)d_in[4];
    const float* b_dec  = (const float*)d_in[5];
    const float* W_full = (const float*)d_in[6];

    float* out       = (float*)d_out;
    float* ctx_out   = out;                       // [B,DE]
    float* alpha_out = out + (size_t)B_ * DE_;    // [B,P]

    char* ws = (char*)d_ws;
    __hip_bfloat16* Bp = (__hip_bfloat16*)ws;                         // 2 MB
    float* att2p = (float*)(ws + 2u * 1024 * 1024);                   // 512 KB
    float* att0  = (float*)(ws + 2u * 1024 * 1024 + 512u * 1024);     // 200 KB
    float* att1  = att0 + M_;                                         // 200 KB

    pack_wenc     <<<NKT,            256, 0, stream>>>(W_enc, Bp);
    att2_kernel   <<<B_,             512, 0, stream>>>(dh, W_dec, b_dec, b_enc, att2p);
    gemm_att      <<<2 * (M_ / BM),  256, 0, stream>>>(enc, Bp, att2p, W_full, att0, att1);
    softmax_kernel<<<B_,             256, 0, stream>>>(att0, att1, alpha_out);
    context_kernel<<<dim3(B_, 2),    256, 0, stream>>>(enc, alpha_out, ctx_out);
}